// Round 5
// baseline (1200.297 us; speedup 1.0000x reference)
//
#include <hip/hip_runtime.h>
#include <hip/hip_bf16.h>
#include <math.h>

#define Bn 64
#define Pn 512
#define Hn 8
#define Ln 6

typedef __bf16 bf16x8 __attribute__((ext_vector_type(8)));
typedef float f32x4 __attribute__((ext_vector_type(4)));

static __device__ __forceinline__ unsigned short f2bf(float f) {
    return __builtin_bit_cast(unsigned short, __float2bfloat16(f));
}
static __device__ __forceinline__ float bf2f(unsigned short v) {
    unsigned int u = ((unsigned int)v) << 16;
    return __builtin_bit_cast(float, u);
}

// ---------- prep: cast/pad Wq,Wk,Wv -> [L][3][H][64 o][64 i] bf16 (zero-padded)
__global__ __launch_bounds__(256)
void prep_wqkv_kernel(const float* __restrict__ Wq, const float* __restrict__ Wk,
                      const float* __restrict__ Wv, unsigned short* __restrict__ out) {
    int idx = blockIdx.x * 256 + threadIdx.x;
    if (idx >= Ln * 3 * Hn * 4096) return;
    int i = idx & 63, o = (idx >> 6) & 63, h = (idx >> 12) & 7, t = idx >> 15;
    int mat = t % 3, l = t / 3;
    float v = 0.f;
    if (o < 49 && i < 49) {
        const float* src = (mat == 0) ? Wq : (mat == 1) ? Wk : Wv;
        v = src[(((size_t)(l * Hn + h) * 49) + o) * 49 + i];
    }
    out[idx] = f2bf(v);
}

// ---------- prep: Weff[l][h][o2 64][o 64] bf16 = sum_dd Wh[l,h,dd,o]*Wout[l,o2,h*49+dd]
__global__ __launch_bounds__(256)
void prep_weff_kernel(const float* __restrict__ Wh, const float* __restrict__ bh,
                      const float* __restrict__ Wout,
                      unsigned short* __restrict__ Weff, float* __restrict__ beff) {
    const int NW = Ln * Hn * 4096;
    int idx = blockIdx.x * 256 + threadIdx.x;
    if (idx < NW) {
        int o = idx & 63, o2 = (idx >> 6) & 63, h = (idx >> 12) & 7, l = idx >> 15;
        float s = 0.f;
        if (o < 49 && o2 < 49) {
            const float* wh = Wh + ((size_t)(l * Hn + h) * 49) * 49 + o;   // [dd] stride 49
            const float* wo = Wout + ((size_t)l * 49 + o2) * 392 + h * 49; // [dd]
            for (int dd = 0; dd < 49; ++dd) s = fmaf(wh[dd * 49], wo[dd], s);
        }
        Weff[idx] = f2bf(s);
    } else if (idx < NW + Ln * 49) {
        int j = idx - NW;
        int l = j / 49, o2 = j % 49;
        const float* wo = Wout + ((size_t)l * 49 + o2) * 392;
        const float* bhl = bh + (size_t)l * 392;
        float s = 0.f;
        for (int cc = 0; cc < 392; ++cc) s = fmaf(bhl[cc], wo[cc], s);
        beff[j] = s;
    }
}

// ---------- prep: cast embedding -> x_bf [32768][64] padded
__global__ __launch_bounds__(256)
void cast_x_kernel(const float* __restrict__ emb, unsigned short* __restrict__ xbf) {
    int idx = blockIdx.x * 256 + threadIdx.x;
    int row = idx >> 6, col = idx & 63;
    float v = (col < 49) ? emb[(size_t)row * 49 + col] : 0.f;
    xbf[idx] = f2bf(v);
}

// ---------- QKV via MFMA: block = 64 rows, loop 24 (mat,h) panels
__global__ __launch_bounds__(256)
void qkv_mfma_kernel(const unsigned short* __restrict__ xbf,
                     const unsigned short* __restrict__ Wqkv,
                     const float* __restrict__ bq_l, const float* __restrict__ bk_l,
                     const float* __restrict__ bv_l,
                     unsigned short* __restrict__ Qb, unsigned short* __restrict__ Kb,
                     unsigned short* __restrict__ Vt,
                     int b_off, int Bc) {
    __shared__ uint4 xlb4[512];
    __shared__ uint4 wlb4[512];
    __shared__ __align__(16) unsigned short stg[64 * 68];
    __shared__ float blds[1536];
    char* xlb = (char*)xlb4;
    char* wlb = (char*)wlb4;
    const int tid = threadIdx.x;
    const int w = tid >> 6, lane = tid & 63, g = lane >> 4, c = lane & 15;
    const int flat = blockIdx.x;
    const int bl = flat % Bc;
    const int tile = flat / Bc;
    const int r0 = bl * Pn + tile * 64;

    for (int t = tid; t < 1536; t += 256) {
        int mat = t >> 9, rem = t & 511, h = rem >> 6, o = rem & 63;
        const float* bb = (mat == 0) ? bq_l : (mat == 1) ? bk_l : bv_l;
        blds[t] = (o < 49) ? bb[h * 49 + o] : 0.f;
    }
    {
        const unsigned short* xg = xbf + ((size_t)b_off * Pn + r0) * 64;
        #pragma unroll
        for (int i = 0; i < 2; ++i) {
            int chunk = tid + i * 256;
            int row = chunk >> 3, c8 = chunk & 7;
            *(uint4*)(xlb + row * 128 + 16 * (c8 ^ (row & 7))) =
                *(const uint4*)(xg + row * 64 + c8 * 8);
        }
    }
    __syncthreads();

    const int rowa = w * 16 + c;
    bf16x8 a0 = *(const bf16x8*)(xlb + rowa * 128 + 16 * ((g    ) ^ (c & 7)));
    bf16x8 a1 = *(const bf16x8*)(xlb + rowa * 128 + 16 * ((g + 4) ^ (c & 7)));

    for (int panel = 0; panel < 24; ++panel) {
        const int mat = panel >> 3, h = panel & 7;
        const unsigned short* wg = Wqkv + (size_t)panel * 4096;
        #pragma unroll
        for (int i = 0; i < 2; ++i) {
            int chunk = tid + i * 256;
            int row = chunk >> 3, c8 = chunk & 7;
            *(uint4*)(wlb + row * 128 + 16 * (c8 ^ (row & 7))) =
                *(const uint4*)(wg + row * 64 + c8 * 8);
        }
        __syncthreads();

        f32x4 acc[4];
        #pragma unroll
        for (int bt = 0; bt < 4; ++bt) acc[bt] = (f32x4){0.f, 0.f, 0.f, 0.f};
        #pragma unroll
        for (int bt = 0; bt < 4; ++bt) {
            int rowb = bt * 16 + c;
            bf16x8 w0 = *(const bf16x8*)(wlb + rowb * 128 + 16 * ((g    ) ^ (rowb & 7)));
            bf16x8 w1 = *(const bf16x8*)(wlb + rowb * 128 + 16 * ((g + 4) ^ (rowb & 7)));
            acc[bt] = __builtin_amdgcn_mfma_f32_16x16x32_bf16(a0, w0, acc[bt], 0, 0, 0);
            acc[bt] = __builtin_amdgcn_mfma_f32_16x16x32_bf16(a1, w1, acc[bt], 0, 0, 0);
        }

        const float* bb = blds + mat * 512 + h * 64;
        if (mat < 2) {
            #pragma unroll
            for (int bt = 0; bt < 4; ++bt)
                #pragma unroll
                for (int r = 0; r < 4; ++r)
                    stg[(w * 16 + 4 * g + r) * 68 + bt * 16 + c] =
                        f2bf(acc[bt][r] + bb[bt * 16 + c]);
        } else {
            #pragma unroll
            for (int bt = 0; bt < 4; ++bt)
                #pragma unroll
                for (int r = 0; r < 4; ++r)
                    stg[(bt * 16 + c) * 68 + (w * 16 + 4 * g + r)] =
                        f2bf(acc[bt][r] + bb[bt * 16 + c]);
        }
        __syncthreads();

        if (mat < 2) {
            unsigned short* outp = (mat == 0) ? Qb : Kb;
            #pragma unroll
            for (int i = 0; i < 4; ++i) {
                int chunk = tid + i * 256;
                int prow = chunk >> 4, c4 = chunk & 15;
                uint2 v = *(const uint2*)((const char*)stg + prow * 136 + c4 * 8);
                int rr = r0 + prow;
                int bl2 = rr >> 9, p = rr & 511;
                *(uint2*)(outp + (((size_t)bl2 * Hn + h) * Pn + p) * 64 + c4 * 4) = v;
            }
        } else {
            const int bl2 = r0 >> 9, p0 = r0 & 511;
            #pragma unroll
            for (int i = 0; i < 4; ++i) {
                int chunk = tid + i * 256;
                int drow = chunk >> 4, c4 = chunk & 15;
                uint2 v = *(const uint2*)((const char*)stg + drow * 136 + c4 * 8);
                *(uint2*)(Vt + (((size_t)bl2 * Hn + h) * 64 + drow) * Pn + p0 + c4 * 4) = v;
            }
        }
    }
}

// ---------- per-head attention: block = 2 waves x 64 q-rows of one (b,h); writes AO bf16
// Swapped QK^T (lane holds 4 consecutive keys), packed P-writes, K/V register prefetch.
__global__ __launch_bounds__(128)
void attn_head_kernel(const unsigned short* __restrict__ Qb,
                      const unsigned short* __restrict__ Kb,
                      const unsigned short* __restrict__ Vt,
                      unsigned short* __restrict__ AO,   // [Bc][H][P][64] bf16
                      int Bc) {
    __shared__ uint4 Klb4[512], Vlb4[512], Plb4[512];
    char* Klb = (char*)Klb4;
    char* Vlb = (char*)Vlb4;
    const int tid = threadIdx.x;
    const int w = tid >> 6, lane = tid & 63, g = lane >> 4, c = lane & 15;
    // swizzled decode: flat = (u>>3)*64 + qt*8 + (u&7); u = bl*8+h
    const int flat = blockIdx.x;
    const int u = (flat >> 6) * 8 + (flat & 7);
    const int qt = (flat >> 3) & 7;
    const size_t bh = (size_t)u;
    const int q0 = qt * 64;
    char* Plw = (char*)Plb4 + w * 4096;

    const float c1 = 1.4426950408889634f / 7.000001f;  // log2(e)/SCALE
    const float c2 = 43.2808512f;                      // 30*log2(e)

    bf16x8 qf[2][2];
    #pragma unroll
    for (int qs = 0; qs < 2; ++qs) {
        const unsigned short* qp = Qb + (bh * Pn + q0 + w * 32 + qs * 16 + c) * 64;
        qf[qs][0] = *(const bf16x8*)(qp + g * 8);
        qf[qs][1] = *(const bf16x8*)(qp + g * 8 + 32);
    }
    float lsum[2] = {0.f, 0.f};
    f32x4 oacc[2][4];
    #pragma unroll
    for (int qs = 0; qs < 2; ++qs)
        #pragma unroll
        for (int dt = 0; dt < 4; ++dt)
            oacc[qs][dt] = (f32x4){0.f, 0.f, 0.f, 0.f};

    const unsigned short* Kg0 = Kb + bh * (size_t)(Pn * 64);
    const unsigned short* Vg0 = Vt + bh * (size_t)(64 * Pn);

    uint4 kpre[4], vpre[4];
    {
        #pragma unroll
        for (int i = 0; i < 4; ++i) {
            int chunk = tid + i * 128, row = chunk >> 3, c8 = chunk & 7;
            kpre[i] = *(const uint4*)(Kg0 + row * 64 + c8 * 8);
            vpre[i] = *(const uint4*)(Vg0 + (size_t)row * Pn + c8 * 8);
        }
    }

    for (int kt = 0; kt < 8; ++kt) {
        // write the prefetched K/V tile to LDS (XOR-swizzled)
        #pragma unroll
        for (int i = 0; i < 4; ++i) {
            int chunk = tid + i * 128, row = chunk >> 3, c8 = chunk & 7;
            *(uint4*)(Klb + row * 128 + 16 * (c8 ^ (row & 7))) = kpre[i];
            *(uint4*)(Vlb + row * 128 + 16 * (c8 ^ (row & 7))) = vpre[i];
        }
        __syncthreads();
        // issue next tile's loads; latency hides under this kt's compute
        if (kt < 7) {
            const unsigned short* Kg = Kg0 + (kt + 1) * (64 * 64);
            const unsigned short* Vg = Vg0 + (kt + 1) * 64;
            #pragma unroll
            for (int i = 0; i < 4; ++i) {
                int chunk = tid + i * 128, row = chunk >> 3, c8 = chunk & 7;
                kpre[i] = *(const uint4*)(Kg + row * 64 + c8 * 8);
                vpre[i] = *(const uint4*)(Vg + (size_t)row * Pn + c8 * 8);
            }
        }

        // scores (transposed): D[key][q] = K·Q^T ; lane holds q=c, keys t*16+4g+r
        #pragma unroll
        for (int t = 0; t < 4; ++t) {
            const int krow = t * 16 + c;
            bf16x8 kf0 = *(const bf16x8*)(Klb + krow * 128 + 16 * ((g    ) ^ (krow & 7)));
            bf16x8 kf1 = *(const bf16x8*)(Klb + krow * 128 + 16 * ((g + 4) ^ (krow & 7)));
            #pragma unroll
            for (int qs = 0; qs < 2; ++qs) {
                f32x4 s4 = {0.f, 0.f, 0.f, 0.f};
                __builtin_amdgcn_s_setprio(1);
                s4 = __builtin_amdgcn_mfma_f32_16x16x32_bf16(kf0, qf[qs][0], s4, 0, 0, 0);
                s4 = __builtin_amdgcn_mfma_f32_16x16x32_bf16(kf1, qf[qs][1], s4, 0, 0, 0);
                __builtin_amdgcn_s_setprio(0);
                float p0, p1, p2, p3;
                {
                    float u0 = fminf(fmaxf(s4[0] * c1, -c2), c2);
                    float u1 = fminf(fmaxf(s4[1] * c1, -c2), c2);
                    float u2 = fminf(fmaxf(s4[2] * c1, -c2), c2);
                    float u3 = fminf(fmaxf(s4[3] * c1, -c2), c2);
                    p0 = exp2f(u0 - c2); p1 = exp2f(u1 - c2);
                    p2 = exp2f(u2 - c2); p3 = exp2f(u3 - c2);
                }
                lsum[qs] += (p0 + p1) + (p2 + p3);
                unsigned int u01, u23;
                asm("v_cvt_pk_bf16_f32 %0, %1, %2" : "=v"(u01) : "v"(p0), "v"(p1));
                asm("v_cvt_pk_bf16_f32 %0, %1, %2" : "=v"(u23) : "v"(p2), "v"(p3));
                const int prow = qs * 16 + c;
                *(uint2*)(Plw + prow * 128 + ((32 * t + 8 * g) ^ ((prow & 7) << 4))) =
                    (uint2){u01, u23};
            }
        }
        asm volatile("s_waitcnt lgkmcnt(0)" ::: "memory");
        __builtin_amdgcn_sched_barrier(0);

        // PV: A = P (row=q), B = V rows
        #pragma unroll
        for (int kk = 0; kk < 2; ++kk) {
            bf16x8 pa0 = *(const bf16x8*)(Plw + (c     ) * 128 + 16 * ((g + 4 * kk) ^ (c & 7)));
            bf16x8 pa1 = *(const bf16x8*)(Plw + (16 + c) * 128 + 16 * ((g + 4 * kk) ^ (c & 7)));
            __builtin_amdgcn_s_setprio(1);
            #pragma unroll
            for (int dt = 0; dt < 4; ++dt) {
                const int vrow = dt * 16 + c;
                bf16x8 vf = *(const bf16x8*)(Vlb + vrow * 128 + 16 * ((g + 4 * kk) ^ (vrow & 7)));
                oacc[0][dt] = __builtin_amdgcn_mfma_f32_16x16x32_bf16(pa0, vf, oacc[0][dt], 0, 0, 0);
                oacc[1][dt] = __builtin_amdgcn_mfma_f32_16x16x32_bf16(pa1, vf, oacc[1][dt], 0, 0, 0);
            }
            __builtin_amdgcn_s_setprio(0);
        }
        __syncthreads();
    }

    // lsum at lane (c,g) is a g-partial for q=c: reduce over g, then fetch per-oacc-row inv
    float rinv[2][4];
    #pragma unroll
    for (int qs = 0; qs < 2; ++qs) {
        float v = lsum[qs];
        v += __shfl_xor(v, 16);
        v += __shfl_xor(v, 32);
        float iv = 1.0f / v;                  // inv total for q = c
        #pragma unroll
        for (int r = 0; r < 4; ++r)
            rinv[qs][r] = __shfl(iv, (lane & 48) | (4 * g + r));
    }
    #pragma unroll
    for (int qs = 0; qs < 2; ++qs)
        #pragma unroll
        for (int dt = 0; dt < 4; ++dt)
            #pragma unroll
            for (int r = 0; r < 4; ++r) {
                int prow = qs * 16 + 4 * g + r;
                int col = dt * 16 + c;
                *(unsigned short*)(Plw + prow * 128 + ((2 * col) ^ ((prow & 7) << 4))) =
                    f2bf(oacc[qs][dt][r] * rinv[qs][r]);
            }
    asm volatile("s_waitcnt lgkmcnt(0)" ::: "memory");
    __builtin_amdgcn_sched_barrier(0);
    #pragma unroll
    for (int i = 0; i < 4; ++i) {
        int chunk = i * 64 + lane;
        int row = chunk >> 3, c8 = chunk & 7;
        uint4 v = *(const uint4*)(Plw + row * 128 + 16 * (c8 ^ (row & 7)));
        size_t grow = bh * Pn + q0 + w * 32 + row;
        *(uint4*)(AO + grow * 64 + c8 * 8) = v;
    }
}

// ---------- out-projection GEMM: x[row][o2] = sum_h AO[h-tile] x Weff[h] ; K = 8x64
__global__ __launch_bounds__(256)
void outproj_mfma_kernel(const unsigned short* __restrict__ AO,    // [Bc][H][P][64]
                         const unsigned short* __restrict__ Weffl, // [8][64][64]
                         const float* __restrict__ beffl,          // [49]
                         unsigned short* __restrict__ xout,        // full [B*512][64]
                         int b_off, int Bc) {
    __shared__ uint4 Alb4[512], Wlb4[512];
    __shared__ __align__(16) unsigned short stg[64 * 68];
    __shared__ float bldc[64];
    char* Alb = (char*)Alb4;
    char* Wlb = (char*)Wlb4;
    const int tid = threadIdx.x;
    const int w = tid >> 6, lane = tid & 63, g = lane >> 4, c = lane & 15;
    const int flat = blockIdx.x;
    const int bl = flat % Bc;
    const int tile = flat / Bc;
    const int p0 = tile * 64;

    if (tid < 64) bldc[tid] = (tid < 49) ? beffl[tid] : 0.f;

    f32x4 acc[4];
    #pragma unroll
    for (int bt = 0; bt < 4; ++bt) acc[bt] = (f32x4){0.f, 0.f, 0.f, 0.f};

    for (int h = 0; h < Hn; ++h) {
        const unsigned short* Ag = AO + (((size_t)bl * Hn + h) * Pn + p0) * 64;
        const unsigned short* Wg = Weffl + (size_t)h * 4096;
        #pragma unroll
        for (int i = 0; i < 2; ++i) {
            int chunk = tid + i * 256;
            int row = chunk >> 3, c8 = chunk & 7;
            *(uint4*)(Alb + row * 128 + 16 * (c8 ^ (row & 7))) =
                *(const uint4*)(Ag + row * 64 + c8 * 8);
            *(uint4*)(Wlb + row * 128 + 16 * (c8 ^ (row & 7))) =
                *(const uint4*)(Wg + row * 64 + c8 * 8);
        }
        __syncthreads();

        const int rowa = w * 16 + c;
        bf16x8 a0 = *(const bf16x8*)(Alb + rowa * 128 + 16 * ((g    ) ^ (c & 7)));
        bf16x8 a1 = *(const bf16x8*)(Alb + rowa * 128 + 16 * ((g + 4) ^ (c & 7)));
        #pragma unroll
        for (int bt = 0; bt < 4; ++bt) {
            int rowb = bt * 16 + c;
            bf16x8 w0 = *(const bf16x8*)(Wlb + rowb * 128 + 16 * ((g    ) ^ (rowb & 7)));
            bf16x8 w1 = *(const bf16x8*)(Wlb + rowb * 128 + 16 * ((g + 4) ^ (rowb & 7)));
            acc[bt] = __builtin_amdgcn_mfma_f32_16x16x32_bf16(a0, w0, acc[bt], 0, 0, 0);
            acc[bt] = __builtin_amdgcn_mfma_f32_16x16x32_bf16(a1, w1, acc[bt], 0, 0, 0);
        }
        __syncthreads();
    }

    #pragma unroll
    for (int bt = 0; bt < 4; ++bt)
        #pragma unroll
        for (int r = 0; r < 4; ++r)
            stg[(w * 16 + 4 * g + r) * 68 + bt * 16 + c] =
                f2bf(acc[bt][r] + bldc[bt * 16 + c]);
    __syncthreads();

    #pragma unroll
    for (int i = 0; i < 4; ++i) {
        int chunk = tid + i * 256;
        int prow = chunk >> 4, c4 = chunk & 15;
        uint2 v = *(const uint2*)((const char*)stg + prow * 136 + c4 * 8);
        size_t grow = (size_t)(b_off + bl) * Pn + p0 + prow;
        *(uint2*)(xout + grow * 64 + c4 * 4) = v;
    }
}

// ---------- mean-pool over P (bf16 input)
__global__ __launch_bounds__(256)
void pool_kernel(const unsigned short* __restrict__ x, float* __restrict__ pooled) {
    __shared__ float red[256];
    const int b = blockIdx.x;
    const int tid = threadIdx.x;
    const int ps = tid >> 6, d = tid & 63;
    float s = 0.f;
    for (int p = ps; p < Pn; p += 4) s += bf2f(x[((size_t)b * Pn + p) * 64 + d]);
    red[tid] = s;
    __syncthreads();
    if (tid < 64) {
        float t = red[tid] + red[tid + 64] + red[tid + 128] + red[tid + 192];
        if (tid < 49) pooled[b * 49 + tid] = t * (1.0f / Pn);
    }
}

// ---------- MLP + log-softmax + NLL
__global__ __launch_bounds__(64)
void head_kernel(const float* __restrict__ pooled, const int* __restrict__ labels,
                 const float* __restrict__ W1, const float* __restrict__ b1,
                 const float* __restrict__ W2, const float* __restrict__ b2,
                 float* __restrict__ out) {
    __shared__ float lloss[64];
    const int b = threadIdx.x;
    float pr[49];
    #pragma unroll
    for (int i = 0; i < 49; ++i) pr[i] = pooled[b * 49 + i];
    float hh[25];
    for (int j = 0; j < 25; ++j) {
        float s = b1[j];
        for (int i = 0; i < 49; ++i) s = fmaf(pr[i], W1[j * 49 + i], s);
        hh[j] = fmaxf(s, 0.f);
    }
    float lg[10];
    float m = -1e30f;
    for (int k = 0; k < 10; ++k) {
        float s = b2[k];
        for (int j = 0; j < 25; ++j) s = fmaf(hh[j], W2[k * 25 + j], s);
        lg[k] = s;
        m = fmaxf(m, s);
    }
    float se = 0.f;
    for (int k = 0; k < 10; ++k) se += __expf(lg[k] - m);
    float lse = m + __logf(se);
    int lbl = labels[b];
    lloss[b] = lse - lg[lbl];
    __syncthreads();
    if (b == 0) {
        float s = 0.f;
        for (int i = 0; i < 64; ++i) s += lloss[i];
        out[0] = s * (1.0f / 64.0f);
    }
}

extern "C" void kernel_launch(void* const* d_in, const int* in_sizes, int n_in,
                              void* d_out, int out_size, void* d_ws, size_t ws_size,
                              hipStream_t stream) {
    const float* emb    = (const float*)d_in[0];
    const int*   labels = (const int*)d_in[1];
    const float* Wq = (const float*)d_in[2];
    const float* bq = (const float*)d_in[3];
    const float* Wk = (const float*)d_in[4];
    const float* bk = (const float*)d_in[5];
    const float* Wv = (const float*)d_in[6];
    const float* bv = (const float*)d_in[7];
    const float* Wh = (const float*)d_in[8];
    const float* bhp = (const float*)d_in[9];
    const float* Wout = (const float*)d_in[10];
    const float* W1 = (const float*)d_in[11];
    const float* b1 = (const float*)d_in[12];
    const float* W2 = (const float*)d_in[13];
    const float* b2 = (const float*)d_in[14];
    float* out = (float*)d_out;

    char* base = (char*)d_ws;
    size_t off = 0;
    auto alloc = [&](size_t bytes) {
        off = (off + 255) & ~(size_t)255;
        char* p = base + off;
        off += bytes;
        return p;
    };

    unsigned short* WqkvB = (unsigned short*)alloc((size_t)Ln * 3 * Hn * 4096 * 2);
    unsigned short* WeffB = (unsigned short*)alloc((size_t)Ln * Hn * 4096 * 2);
    float*          beffB = (float*)alloc((size_t)Ln * 49 * 4);
    unsigned short* xA    = (unsigned short*)alloc((size_t)Bn * Pn * 64 * 2);
    unsigned short* xB    = (unsigned short*)alloc((size_t)Bn * Pn * 64 * 2);
    float*          pooled = (float*)alloc((size_t)Bn * 49 * 4);

    const size_t per_b = 4 * ((size_t)Hn * Pn * 64 * 2);   // Q + K + Vt + AO bf16
    size_t fixed = (off + 255) & ~(size_t)255;
    int Bc = Bn;
    while (Bc > 8 && fixed + (size_t)Bc * per_b + 4096 > ws_size) Bc >>= 1;

    unsigned short* Qb  = (unsigned short*)alloc((size_t)Bc * Hn * Pn * 64 * 2);
    unsigned short* Kb  = (unsigned short*)alloc((size_t)Bc * Hn * Pn * 64 * 2);
    unsigned short* Vtb = (unsigned short*)alloc((size_t)Bc * Hn * Pn * 64 * 2);
    unsigned short* AOb = (unsigned short*)alloc((size_t)Bc * Hn * Pn * 64 * 2);

    prep_wqkv_kernel<<<(Ln * 3 * Hn * 4096 + 255) / 256, 256, 0, stream>>>(Wq, Wk, Wv, WqkvB);
    prep_weff_kernel<<<(Ln * Hn * 4096 + Ln * 49 + 255) / 256, 256, 0, stream>>>(Wh, bhp, Wout, WeffB, beffB);
    cast_x_kernel<<<(Bn * Pn * 64) / 256, 256, 0, stream>>>(emb, xA);

    unsigned short* cur = xA;
    unsigned short* nxt = xB;
    for (int l = 0; l < Ln; ++l) {
        const unsigned short* Wqkv_l = WqkvB + (size_t)l * 3 * Hn * 4096;
        const unsigned short* Weff_l = WeffB + (size_t)l * Hn * 4096;
        const float* beff_l = beffB + (size_t)l * 49;
        const float* bq_l = bq + (size_t)l * Hn * 49;
        const float* bk_l = bk + (size_t)l * Hn * 49;
        const float* bv_l = bv + (size_t)l * Hn * 49;

        for (int b0 = 0; b0 < Bn; b0 += Bc) {
            qkv_mfma_kernel<<<Bc * 8, 256, 0, stream>>>(cur, Wqkv_l, bq_l, bk_l, bv_l,
                                                        Qb, Kb, Vtb, b0, Bc);
            attn_head_kernel<<<Bc * 64, 128, 0, stream>>>(Qb, Kb, Vtb, AOb, Bc);
            outproj_mfma_kernel<<<Bc * 8, 256, 0, stream>>>(AOb, Weff_l, beff_l, nxt, b0, Bc);
        }
        unsigned short* tmp = cur; cur = nxt; nxt = tmp;
    }

    pool_kernel<<<Bn, 256, 0, stream>>>(cur, pooled);
    head_kernel<<<1, 64, 0, stream>>>(pooled, labels, W1, b1, W2, b2, out);
}

// Round 6
// 695.760 us; speedup vs baseline: 1.7252x; 1.7252x over previous
//
#include <hip/hip_runtime.h>
#include <hip/hip_bf16.h>
#include <math.h>

#define Bn 64
#define Pn 512
#define Hn 8
#define Ln 6

typedef __bf16 bf16x8 __attribute__((ext_vector_type(8)));
typedef float f32x4 __attribute__((ext_vector_type(4)));

#define VMCNT(n) asm volatile("s_waitcnt vmcnt(" #n ")" ::: "memory")

static __device__ __forceinline__ unsigned short f2bf(float f) {
    return __builtin_bit_cast(unsigned short, __float2bfloat16(f));
}
static __device__ __forceinline__ float bf2f(unsigned short v) {
    unsigned int u = ((unsigned int)v) << 16;
    return __builtin_bit_cast(float, u);
}

// ---------- prep: cast/pad Wq,Wk,Wv -> [L][3][H][64 o][64 i] bf16 (zero-padded)
__global__ __launch_bounds__(256)
void prep_wqkv_kernel(const float* __restrict__ Wq, const float* __restrict__ Wk,
                      const float* __restrict__ Wv, unsigned short* __restrict__ out) {
    int idx = blockIdx.x * 256 + threadIdx.x;
    if (idx >= Ln * 3 * Hn * 4096) return;
    int i = idx & 63, o = (idx >> 6) & 63, h = (idx >> 12) & 7, t = idx >> 15;
    int mat = t % 3, l = t / 3;
    float v = 0.f;
    if (o < 49 && i < 49) {
        const float* src = (mat == 0) ? Wq : (mat == 1) ? Wk : Wv;
        v = src[(((size_t)(l * Hn + h) * 49) + o) * 49 + i];
    }
    out[idx] = f2bf(v);
}

// ---------- prep: Weff[l][h][o2 64][o 64] bf16 = sum_dd Wh[l,h,dd,o]*Wout[l,o2,h*49+dd]
__global__ __launch_bounds__(256)
void prep_weff_kernel(const float* __restrict__ Wh, const float* __restrict__ bh,
                      const float* __restrict__ Wout,
                      unsigned short* __restrict__ Weff, float* __restrict__ beff) {
    const int NW = Ln * Hn * 4096;
    int idx = blockIdx.x * 256 + threadIdx.x;
    if (idx < NW) {
        int o = idx & 63, o2 = (idx >> 6) & 63, h = (idx >> 12) & 7, l = idx >> 15;
        float s = 0.f;
        if (o < 49 && o2 < 49) {
            const float* wh = Wh + ((size_t)(l * Hn + h) * 49) * 49 + o;   // [dd] stride 49
            const float* wo = Wout + ((size_t)l * 49 + o2) * 392 + h * 49; // [dd]
            for (int dd = 0; dd < 49; ++dd) s = fmaf(wh[dd * 49], wo[dd], s);
        }
        Weff[idx] = f2bf(s);
    } else if (idx < NW + Ln * 49) {
        int j = idx - NW;
        int l = j / 49, o2 = j % 49;
        const float* wo = Wout + ((size_t)l * 49 + o2) * 392;
        const float* bhl = bh + (size_t)l * 392;
        float s = 0.f;
        for (int cc = 0; cc < 392; ++cc) s = fmaf(bhl[cc], wo[cc], s);
        beff[j] = s;
    }
}

// ---------- prep: cast embedding -> x_bf [32768][64] padded
__global__ __launch_bounds__(256)
void cast_x_kernel(const float* __restrict__ emb, unsigned short* __restrict__ xbf) {
    int idx = blockIdx.x * 256 + threadIdx.x;
    int row = idx >> 6, col = idx & 63;
    float v = (col < 49) ? emb[(size_t)row * 49 + col] : 0.f;
    xbf[idx] = f2bf(v);
}

// ---------- QKV via MFMA: block = 64 rows, loop 24 (mat,h) panels
__global__ __launch_bounds__(256)
void qkv_mfma_kernel(const unsigned short* __restrict__ xbf,
                     const unsigned short* __restrict__ Wqkv,
                     const float* __restrict__ bq_l, const float* __restrict__ bk_l,
                     const float* __restrict__ bv_l,
                     unsigned short* __restrict__ Qb, unsigned short* __restrict__ Kb,
                     unsigned short* __restrict__ Vt,
                     int b_off, int Bc) {
    __shared__ uint4 xlb4[512];
    __shared__ uint4 wlb4[512];
    __shared__ __align__(16) unsigned short stg[64 * 68];
    __shared__ float blds[1536];
    char* xlb = (char*)xlb4;
    char* wlb = (char*)wlb4;
    const int tid = threadIdx.x;
    const int w = tid >> 6, lane = tid & 63, g = lane >> 4, c = lane & 15;
    const int flat = blockIdx.x;
    const int bl = flat % Bc;
    const int tile = flat / Bc;
    const int r0 = bl * Pn + tile * 64;

    for (int t = tid; t < 1536; t += 256) {
        int mat = t >> 9, rem = t & 511, h = rem >> 6, o = rem & 63;
        const float* bb = (mat == 0) ? bq_l : (mat == 1) ? bk_l : bv_l;
        blds[t] = (o < 49) ? bb[h * 49 + o] : 0.f;
    }
    {
        const unsigned short* xg = xbf + ((size_t)b_off * Pn + r0) * 64;
        #pragma unroll
        for (int i = 0; i < 2; ++i) {
            int chunk = tid + i * 256;
            int row = chunk >> 3, c8 = chunk & 7;
            *(uint4*)(xlb + row * 128 + 16 * (c8 ^ (row & 7))) =
                *(const uint4*)(xg + row * 64 + c8 * 8);
        }
    }
    __syncthreads();

    const int rowa = w * 16 + c;
    bf16x8 a0 = *(const bf16x8*)(xlb + rowa * 128 + 16 * ((g    ) ^ (c & 7)));
    bf16x8 a1 = *(const bf16x8*)(xlb + rowa * 128 + 16 * ((g + 4) ^ (c & 7)));

    for (int panel = 0; panel < 24; ++panel) {
        const int mat = panel >> 3, h = panel & 7;
        const unsigned short* wg = Wqkv + (size_t)panel * 4096;
        #pragma unroll
        for (int i = 0; i < 2; ++i) {
            int chunk = tid + i * 256;
            int row = chunk >> 3, c8 = chunk & 7;
            *(uint4*)(wlb + row * 128 + 16 * (c8 ^ (row & 7))) =
                *(const uint4*)(wg + row * 64 + c8 * 8);
        }
        __syncthreads();

        f32x4 acc[4];
        #pragma unroll
        for (int bt = 0; bt < 4; ++bt) acc[bt] = (f32x4){0.f, 0.f, 0.f, 0.f};
        #pragma unroll
        for (int bt = 0; bt < 4; ++bt) {
            int rowb = bt * 16 + c;
            bf16x8 w0 = *(const bf16x8*)(wlb + rowb * 128 + 16 * ((g    ) ^ (rowb & 7)));
            bf16x8 w1 = *(const bf16x8*)(wlb + rowb * 128 + 16 * ((g + 4) ^ (rowb & 7)));
            acc[bt] = __builtin_amdgcn_mfma_f32_16x16x32_bf16(a0, w0, acc[bt], 0, 0, 0);
            acc[bt] = __builtin_amdgcn_mfma_f32_16x16x32_bf16(a1, w1, acc[bt], 0, 0, 0);
        }

        const float* bb = blds + mat * 512 + h * 64;
        if (mat < 2) {
            #pragma unroll
            for (int bt = 0; bt < 4; ++bt)
                #pragma unroll
                for (int r = 0; r < 4; ++r)
                    stg[(w * 16 + 4 * g + r) * 68 + bt * 16 + c] =
                        f2bf(acc[bt][r] + bb[bt * 16 + c]);
        } else {
            #pragma unroll
            for (int bt = 0; bt < 4; ++bt)
                #pragma unroll
                for (int r = 0; r < 4; ++r)
                    stg[(bt * 16 + c) * 68 + (w * 16 + 4 * g + r)] =
                        f2bf(acc[bt][r] + bb[bt * 16 + c]);
        }
        __syncthreads();

        if (mat < 2) {
            unsigned short* outp = (mat == 0) ? Qb : Kb;
            #pragma unroll
            for (int i = 0; i < 4; ++i) {
                int chunk = tid + i * 256;
                int prow = chunk >> 4, c4 = chunk & 15;
                uint2 v = *(const uint2*)((const char*)stg + prow * 136 + c4 * 8);
                int rr = r0 + prow;
                int bl2 = rr >> 9, p = rr & 511;
                *(uint2*)(outp + (((size_t)bl2 * Hn + h) * Pn + p) * 64 + c4 * 4) = v;
            }
        } else {
            const int bl2 = r0 >> 9, p0 = r0 & 511;
            #pragma unroll
            for (int i = 0; i < 4; ++i) {
                int chunk = tid + i * 256;
                int drow = chunk >> 4, c4 = chunk & 15;
                uint2 v = *(const uint2*)((const char*)stg + drow * 136 + c4 * 8);
                *(uint2*)(Vt + (((size_t)bl2 * Hn + h) * 64 + drow) * Pn + p0 + c4 * 4) = v;
            }
        }
    }
}

// ---------- per-head attention: 4 waves x 128 q-rows of one (b,h); async dbuf K/V staging
__global__ __launch_bounds__(256)
void attn_head_kernel(const unsigned short* __restrict__ Qb,
                      const unsigned short* __restrict__ Kb,
                      const unsigned short* __restrict__ Vt,
                      unsigned short* __restrict__ AO,   // [Bc][H][P][64] bf16
                      int Bc) {
    // 48 KiB: K dbuf 2x8K | V dbuf 2x8K | P 4x4K
    __shared__ uint4 lds4[3072];
    char* ldsb = (char*)lds4;
    const int tid = threadIdx.x;
    const int w = tid >> 6, lane = tid & 63, g = lane >> 4, c = lane & 15;
    // swizzle: flat = a*32 + qt*8 + x ; bh = a*8+x -> all q-tiles of (b,h) on one XCD
    const int flat = blockIdx.x;
    const int x = flat & 7;
    const int qt = (flat >> 3) & 3;
    const int a = flat >> 5;
    const size_t bh = (size_t)(a * 8 + x);
    const int q0 = qt * 128;
    char* Plw = ldsb + 32768 + w * 4096;

    const float c1 = 1.4426950408889634f / 7.000001f;  // log2(e)/SCALE
    const float c2 = 43.2808512f;                      // 30*log2(e)

    bf16x8 qf[2][2];
    #pragma unroll
    for (int qs = 0; qs < 2; ++qs) {
        const unsigned short* qp = Qb + (bh * Pn + q0 + w * 32 + qs * 16 + c) * 64;
        qf[qs][0] = *(const bf16x8*)(qp + g * 8);
        qf[qs][1] = *(const bf16x8*)(qp + g * 8 + 32);
    }
    float lsum[2] = {0.f, 0.f};
    f32x4 oacc[2][4];
    #pragma unroll
    for (int qs = 0; qs < 2; ++qs)
        #pragma unroll
        for (int dt = 0; dt < 4; ++dt)
            oacc[qs][dt] = (f32x4){0.f, 0.f, 0.f, 0.f};

    const unsigned short* Kg0 = Kb + bh * (size_t)(Pn * 64);
    const unsigned short* Vg0 = Vt + bh * (size_t)(64 * Pn);

    // async stage one K/V tile into buf (linear LDS dest + inverse-swizzled global src)
    auto stage = [&](int kt, int buf) {
        const unsigned short* Kg = Kg0 + kt * (64 * 64);
        const unsigned short* Vg = Vg0 + kt * 64;
        #pragma unroll
        for (int j = 0; j < 2; ++j) {
            int chunk = w * 128 + j * 64 + lane;
            int row = chunk >> 3, c8 = chunk & 7;
            int swc = (c8 ^ (row & 7)) << 3;
            __builtin_amdgcn_global_load_lds(
                (const __attribute__((address_space(1))) void*)(Kg + row * 64 + swc),
                (__attribute__((address_space(3))) void*)(ldsb + buf * 8192 + w * 2048 + j * 1024),
                16, 0, 0);
            __builtin_amdgcn_global_load_lds(
                (const __attribute__((address_space(1))) void*)(Vg + (size_t)row * Pn + swc),
                (__attribute__((address_space(3))) void*)(ldsb + 16384 + buf * 8192 + w * 2048 + j * 1024),
                16, 0, 0);
        }
    };

    stage(0, 0);

    #pragma unroll 2
    for (int kt = 0; kt < 8; ++kt) {
        const int cur = kt & 1;
        if (kt < 7) {
            stage(kt + 1, cur ^ 1);
            VMCNT(4);                       // current tile's 4 loads done; next 4 in flight
        } else {
            VMCNT(0);
        }
        __builtin_amdgcn_s_barrier();
        __builtin_amdgcn_sched_barrier(0);

        char* Klb = ldsb + cur * 8192;
        char* Vlb = ldsb + 16384 + cur * 8192;

        // scores (swapped): D[key][q] ; lane(g,c) reg r = score(key=t*16+4g+r, q=c)
        #pragma unroll
        for (int t = 0; t < 4; ++t) {
            const int krow = t * 16 + c;
            bf16x8 kf0 = *(const bf16x8*)(Klb + krow * 128 + 16 * ((g    ) ^ (krow & 7)));
            bf16x8 kf1 = *(const bf16x8*)(Klb + krow * 128 + 16 * ((g + 4) ^ (krow & 7)));
            #pragma unroll
            for (int qs = 0; qs < 2; ++qs) {
                f32x4 s4 = {0.f, 0.f, 0.f, 0.f};
                __builtin_amdgcn_s_setprio(1);
                s4 = __builtin_amdgcn_mfma_f32_16x16x32_bf16(kf0, qf[qs][0], s4, 0, 0, 0);
                s4 = __builtin_amdgcn_mfma_f32_16x16x32_bf16(kf1, qf[qs][1], s4, 0, 0, 0);
                __builtin_amdgcn_s_setprio(0);
                float p0, p1, p2, p3;
                {
                    float u0 = fminf(fmaxf(s4[0] * c1, -c2), c2);
                    float u1 = fminf(fmaxf(s4[1] * c1, -c2), c2);
                    float u2 = fminf(fmaxf(s4[2] * c1, -c2), c2);
                    float u3 = fminf(fmaxf(s4[3] * c1, -c2), c2);
                    p0 = exp2f(u0 - c2); p1 = exp2f(u1 - c2);
                    p2 = exp2f(u2 - c2); p3 = exp2f(u3 - c2);
                }
                lsum[qs] += (p0 + p1) + (p2 + p3);
                unsigned int u01, u23;
                asm("v_cvt_pk_bf16_f32 %0, %1, %2" : "=v"(u01) : "v"(p0), "v"(p1));
                asm("v_cvt_pk_bf16_f32 %0, %1, %2" : "=v"(u23) : "v"(p2), "v"(p3));
                const int prow = qs * 16 + c;
                *(uint2*)(Plw + prow * 128 + ((32 * t + 8 * g) ^ ((prow & 7) << 4))) =
                    (uint2){u01, u23};
            }
        }
        asm volatile("s_waitcnt lgkmcnt(0)" ::: "memory");
        __builtin_amdgcn_sched_barrier(0);

        // PV: A = P (row=q), B = V^T rows
        #pragma unroll
        for (int kk = 0; kk < 2; ++kk) {
            bf16x8 pa0 = *(const bf16x8*)(Plw + (c     ) * 128 + 16 * ((g + 4 * kk) ^ (c & 7)));
            bf16x8 pa1 = *(const bf16x8*)(Plw + (16 + c) * 128 + 16 * ((g + 4 * kk) ^ (c & 7)));
            __builtin_amdgcn_s_setprio(1);
            #pragma unroll
            for (int dt = 0; dt < 4; ++dt) {
                const int vrow = dt * 16 + c;
                bf16x8 vf = *(const bf16x8*)(Vlb + vrow * 128 + 16 * ((g + 4 * kk) ^ (vrow & 7)));
                oacc[0][dt] = __builtin_amdgcn_mfma_f32_16x16x32_bf16(pa0, vf, oacc[0][dt], 0, 0, 0);
                oacc[1][dt] = __builtin_amdgcn_mfma_f32_16x16x32_bf16(pa1, vf, oacc[1][dt], 0, 0, 0);
            }
            __builtin_amdgcn_s_setprio(0);
        }
        __builtin_amdgcn_sched_barrier(0);
        __builtin_amdgcn_s_barrier();      // all waves done reading buf before restage
    }

    // lsum at lane (g,c) is a g-partial for q=c: reduce over g, fetch per-oacc-row inv
    float rinv[2][4];
    #pragma unroll
    for (int qs = 0; qs < 2; ++qs) {
        float v = lsum[qs];
        v += __shfl_xor(v, 16);
        v += __shfl_xor(v, 32);
        float iv = 1.0f / v;                  // inv total for q = c
        #pragma unroll
        for (int r = 0; r < 4; ++r)
            rinv[qs][r] = __shfl(iv, (lane & 48) | (4 * g + r));
    }
    #pragma unroll
    for (int qs = 0; qs < 2; ++qs)
        #pragma unroll
        for (int dt = 0; dt < 4; ++dt)
            #pragma unroll
            for (int r = 0; r < 4; ++r) {
                int prow = qs * 16 + 4 * g + r;
                int col = dt * 16 + c;
                *(unsigned short*)(Plw + prow * 128 + ((2 * col) ^ ((prow & 7) << 4))) =
                    f2bf(oacc[qs][dt][r] * rinv[qs][r]);
            }
    asm volatile("s_waitcnt lgkmcnt(0)" ::: "memory");
    __builtin_amdgcn_sched_barrier(0);
    #pragma unroll
    for (int i = 0; i < 4; ++i) {
        int chunk = i * 64 + lane;
        int row = chunk >> 3, c8 = chunk & 7;
        uint4 v = *(const uint4*)(Plw + row * 128 + 16 * (c8 ^ (row & 7)));
        size_t grow = bh * Pn + q0 + w * 32 + row;
        *(uint4*)(AO + grow * 64 + c8 * 8) = v;
    }
}

// ---------- out-projection GEMM: x[row][o2] = sum_h AO[h-tile] x Weff[h] ; K = 8x64
__global__ __launch_bounds__(256)
void outproj_mfma_kernel(const unsigned short* __restrict__ AO,    // [Bc][H][P][64]
                         const unsigned short* __restrict__ Weffl, // [8][64][64]
                         const float* __restrict__ beffl,          // [49]
                         unsigned short* __restrict__ xout,        // full [B*512][64]
                         int b_off, int Bc) {
    __shared__ uint4 Alb4[512], Wlb4[512];
    __shared__ __align__(16) unsigned short stg[64 * 68];
    __shared__ float bldc[64];
    char* Alb = (char*)Alb4;
    char* Wlb = (char*)Wlb4;
    const int tid = threadIdx.x;
    const int w = tid >> 6, lane = tid & 63, g = lane >> 4, c = lane & 15;
    const int flat = blockIdx.x;
    const int bl = flat % Bc;
    const int tile = flat / Bc;
    const int p0 = tile * 64;

    if (tid < 64) bldc[tid] = (tid < 49) ? beffl[tid] : 0.f;

    f32x4 acc[4];
    #pragma unroll
    for (int bt = 0; bt < 4; ++bt) acc[bt] = (f32x4){0.f, 0.f, 0.f, 0.f};

    for (int h = 0; h < Hn; ++h) {
        const unsigned short* Ag = AO + (((size_t)bl * Hn + h) * Pn + p0) * 64;
        const unsigned short* Wg = Weffl + (size_t)h * 4096;
        #pragma unroll
        for (int i = 0; i < 2; ++i) {
            int chunk = tid + i * 256;
            int row = chunk >> 3, c8 = chunk & 7;
            *(uint4*)(Alb + row * 128 + 16 * (c8 ^ (row & 7))) =
                *(const uint4*)(Ag + row * 64 + c8 * 8);
            *(uint4*)(Wlb + row * 128 + 16 * (c8 ^ (row & 7))) =
                *(const uint4*)(Wg + row * 64 + c8 * 8);
        }
        __syncthreads();

        const int rowa = w * 16 + c;
        bf16x8 a0 = *(const bf16x8*)(Alb + rowa * 128 + 16 * ((g    ) ^ (c & 7)));
        bf16x8 a1 = *(const bf16x8*)(Alb + rowa * 128 + 16 * ((g + 4) ^ (c & 7)));
        #pragma unroll
        for (int bt = 0; bt < 4; ++bt) {
            int rowb = bt * 16 + c;
            bf16x8 w0 = *(const bf16x8*)(Wlb + rowb * 128 + 16 * ((g    ) ^ (rowb & 7)));
            bf16x8 w1 = *(const bf16x8*)(Wlb + rowb * 128 + 16 * ((g + 4) ^ (rowb & 7)));
            acc[bt] = __builtin_amdgcn_mfma_f32_16x16x32_bf16(a0, w0, acc[bt], 0, 0, 0);
            acc[bt] = __builtin_amdgcn_mfma_f32_16x16x32_bf16(a1, w1, acc[bt], 0, 0, 0);
        }
        __syncthreads();
    }

    #pragma unroll
    for (int bt = 0; bt < 4; ++bt)
        #pragma unroll
        for (int r = 0; r < 4; ++r)
            stg[(w * 16 + 4 * g + r) * 68 + bt * 16 + c] =
                f2bf(acc[bt][r] + bldc[bt * 16 + c]);
    __syncthreads();

    #pragma unroll
    for (int i = 0; i < 4; ++i) {
        int chunk = tid + i * 256;
        int prow = chunk >> 4, c4 = chunk & 15;
        uint2 v = *(const uint2*)((const char*)stg + prow * 136 + c4 * 8);
        size_t grow = (size_t)(b_off + bl) * Pn + p0 + prow;
        *(uint2*)(xout + grow * 64 + c4 * 4) = v;
    }
}

// ---------- mean-pool over P (bf16 input)
__global__ __launch_bounds__(256)
void pool_kernel(const unsigned short* __restrict__ x, float* __restrict__ pooled) {
    __shared__ float red[256];
    const int b = blockIdx.x;
    const int tid = threadIdx.x;
    const int ps = tid >> 6, d = tid & 63;
    float s = 0.f;
    for (int p = ps; p < Pn; p += 4) s += bf2f(x[((size_t)b * Pn + p) * 64 + d]);
    red[tid] = s;
    __syncthreads();
    if (tid < 64) {
        float t = red[tid] + red[tid + 64] + red[tid + 128] + red[tid + 192];
        if (tid < 49) pooled[b * 49 + tid] = t * (1.0f / Pn);
    }
}

// ---------- MLP + log-softmax + NLL
__global__ __launch_bounds__(64)
void head_kernel(const float* __restrict__ pooled, const int* __restrict__ labels,
                 const float* __restrict__ W1, const float* __restrict__ b1,
                 const float* __restrict__ W2, const float* __restrict__ b2,
                 float* __restrict__ out) {
    __shared__ float lloss[64];
    const int b = threadIdx.x;
    float pr[49];
    #pragma unroll
    for (int i = 0; i < 49; ++i) pr[i] = pooled[b * 49 + i];
    float hh[25];
    for (int j = 0; j < 25; ++j) {
        float s = b1[j];
        for (int i = 0; i < 49; ++i) s = fmaf(pr[i], W1[j * 49 + i], s);
        hh[j] = fmaxf(s, 0.f);
    }
    float lg[10];
    float m = -1e30f;
    for (int k = 0; k < 10; ++k) {
        float s = b2[k];
        for (int j = 0; j < 25; ++j) s = fmaf(hh[j], W2[k * 25 + j], s);
        lg[k] = s;
        m = fmaxf(m, s);
    }
    float se = 0.f;
    for (int k = 0; k < 10; ++k) se += __expf(lg[k] - m);
    float lse = m + __logf(se);
    int lbl = labels[b];
    lloss[b] = lse - lg[lbl];
    __syncthreads();
    if (b == 0) {
        float s = 0.f;
        for (int i = 0; i < 64; ++i) s += lloss[i];
        out[0] = s * (1.0f / 64.0f);
    }
}

extern "C" void kernel_launch(void* const* d_in, const int* in_sizes, int n_in,
                              void* d_out, int out_size, void* d_ws, size_t ws_size,
                              hipStream_t stream) {
    const float* emb    = (const float*)d_in[0];
    const int*   labels = (const int*)d_in[1];
    const float* Wq = (const float*)d_in[2];
    const float* bq = (const float*)d_in[3];
    const float* Wk = (const float*)d_in[4];
    const float* bk = (const float*)d_in[5];
    const float* Wv = (const float*)d_in[6];
    const float* bv = (const float*)d_in[7];
    const float* Wh = (const float*)d_in[8];
    const float* bhp = (const float*)d_in[9];
    const float* Wout = (const float*)d_in[10];
    const float* W1 = (const float*)d_in[11];
    const float* b1 = (const float*)d_in[12];
    const float* W2 = (const float*)d_in[13];
    const float* b2 = (const float*)d_in[14];
    float* out = (float*)d_out;

    char* base = (char*)d_ws;
    size_t off = 0;
    auto alloc = [&](size_t bytes) {
        off = (off + 255) & ~(size_t)255;
        char* p = base + off;
        off += bytes;
        return p;
    };

    unsigned short* WqkvB = (unsigned short*)alloc((size_t)Ln * 3 * Hn * 4096 * 2);
    unsigned short* WeffB = (unsigned short*)alloc((size_t)Ln * Hn * 4096 * 2);
    float*          beffB = (float*)alloc((size_t)Ln * 49 * 4);
    unsigned short* xA    = (unsigned short*)alloc((size_t)Bn * Pn * 64 * 2);
    unsigned short* xB    = (unsigned short*)alloc((size_t)Bn * Pn * 64 * 2);
    float*          pooled = (float*)alloc((size_t)Bn * 49 * 4);

    const size_t per_b = 4 * ((size_t)Hn * Pn * 64 * 2);   // Q + K + Vt + AO bf16
    size_t fixed = (off + 255) & ~(size_t)255;
    int Bc = Bn;
    while (Bc > 8 && fixed + (size_t)Bc * per_b + 4096 > ws_size) Bc >>= 1;

    unsigned short* Qb  = (unsigned short*)alloc((size_t)Bc * Hn * Pn * 64 * 2);
    unsigned short* Kb  = (unsigned short*)alloc((size_t)Bc * Hn * Pn * 64 * 2);
    unsigned short* Vtb = (unsigned short*)alloc((size_t)Bc * Hn * Pn * 64 * 2);
    unsigned short* AOb = (unsigned short*)alloc((size_t)Bc * Hn * Pn * 64 * 2);

    prep_wqkv_kernel<<<(Ln * 3 * Hn * 4096 + 255) / 256, 256, 0, stream>>>(Wq, Wk, Wv, WqkvB);
    prep_weff_kernel<<<(Ln * Hn * 4096 + Ln * 49 + 255) / 256, 256, 0, stream>>>(Wh, bhp, Wout, WeffB, beffB);
    cast_x_kernel<<<(Bn * Pn * 64) / 256, 256, 0, stream>>>(emb, xA);

    unsigned short* cur = xA;
    unsigned short* nxt = xB;
    for (int l = 0; l < Ln; ++l) {
        const unsigned short* Wqkv_l = WqkvB + (size_t)l * 3 * Hn * 4096;
        const unsigned short* Weff_l = WeffB + (size_t)l * Hn * 4096;
        const float* beff_l = beffB + (size_t)l * 49;
        const float* bq_l = bq + (size_t)l * Hn * 49;
        const float* bk_l = bk + (size_t)l * Hn * 49;
        const float* bv_l = bv + (size_t)l * Hn * 49;

        for (int b0 = 0; b0 < Bn; b0 += Bc) {
            qkv_mfma_kernel<<<Bc * 8, 256, 0, stream>>>(cur, Wqkv_l, bq_l, bk_l, bv_l,
                                                        Qb, Kb, Vtb, b0, Bc);
            attn_head_kernel<<<Bc * 32, 256, 0, stream>>>(Qb, Kb, Vtb, AOb, Bc);
            outproj_mfma_kernel<<<Bc * 8, 256, 0, stream>>>(AOb, Weff_l, beff_l, nxt, b0, Bc);
        }
        unsigned short* tmp = cur; cur = nxt; nxt = tmp;
    }

    pool_kernel<<<Bn, 256, 0, stream>>>(cur, pooled);
    head_kernel<<<1, 64, 0, stream>>>(pooled, labels, W1, b1, W2, b2, out);
}